// Round 8
// baseline (372.106 us; speedup 1.0000x reference)
//
#include <hip/hip_runtime.h>
#include <cstdint>
#include <cstddef>

typedef __bf16 bf16;
typedef __bf16 bf16x4 __attribute__((ext_vector_type(4)));
typedef __bf16 bf16x8 __attribute__((ext_vector_type(8)));
typedef float  f32x4  __attribute__((ext_vector_type(4)));

#define MDIM 2048
#define NDIM 4096
#define KDIM 4096
#define FLOATMAX 3.402823466e38f

// ---------------- fp32 -> bf16 conversion (one launch for both tensors) ----------------
__global__ void cvt2_f32_to_bf16(const float* __restrict__ x, const float* __restrict__ w,
                                 bf16* __restrict__ xb, bf16* __restrict__ wb,
                                 int xn4, int wn4) {
    const int stride = gridDim.x * blockDim.x;
    int i = blockIdx.x * blockDim.x + threadIdx.x;
    for (int k = i; k < xn4; k += stride) {
        f32x4 v = reinterpret_cast<const f32x4*>(x)[k];
        reinterpret_cast<bf16x4*>(xb)[k] = __builtin_convertvector(v, bf16x4);
    }
    for (int k = i; k < wn4; k += stride) {
        f32x4 v = reinterpret_cast<const f32x4*>(w)[k];
        reinterpret_cast<bf16x4*>(wb)[k] = __builtin_convertvector(v, bf16x4);
    }
}

// async global->LDS, 16B per lane (HW: wave-uniform LDS base + lane*16)
__device__ __forceinline__ void g2lds16(const bf16* g, bf16* l) {
    __builtin_amdgcn_global_load_lds(
        (const __attribute__((address_space(1))) uint32_t*)g,
        (__attribute__((address_space(3))) uint32_t*)l, 16, 0, 0);
}

#define WAITVM(N) asm volatile("s_waitcnt vmcnt(" #N ")" ::: "memory")

// ---------------- MAM main kernel ----------------
// Block tile 128(m) x 128(n); 256 threads = 4 waves in 2(m) x 2(n); wave tile 64x64.
// R7 LESSON: spill-free 64x64 at 1 wave/SIMD (occupancy 11%) is stall-bound:
// ~3700 cyc/stage vs ~800 cyc pipe work -- the __syncthreads vmcnt(0) drain +
// ds_read/MFMA latency with no co-resident wave to overlap.
// THIS VERSION: BK=32, 4 LDS buffers (4 x 16KB = 64KB -> 2 blocks/CU), depth-3
// prefetch with counted vmcnt (T3/T4): per stage issue pf(s+3), end with
// s_waitcnt vmcnt(8) + raw s_barrier -- pf(s+1) (older than the newest 8 VMEM ops)
// is complete, pf(s+2)/pf(s+3) stay IN FLIGHT across the barrier. Loads fly ~3
// stages (~1300 cyc) before use -> HBM latency hidden, no drain-to-0 in the loop.
// Buffer-reuse safety: pf(s+3) writes buf[(s-1)&3]; all its readers passed the
// end-of-(s-1) barrier before any wave reaches stage s to issue pf(s+3).
// Registers: only 4 B-frags + 1 A-frag + 1 s-temp resident (~170 total demand)
// -> no cap needed, no spill, <=256 -> 2 waves/SIMD (8 waves/CU).
// K: 128 stages of BK=32 (1 ACCBLOCK each); SPLITS=2 sequential: after stage 63
// store partial (mx+mn) to out (race-free, idempotent), reset; epilogue adds
// stored + split1 + bias (same-thread RMW). 2-op max/min per stage (VALU floor
// 27us, still under the 41us LDS-read floor).
// Staging uses XOR chunk swizzle so fragment ds_read_b128 is 2-way conflict-free.
// XCD swizzle: 512 wgs = 8 XCDs x 64; each XCD gets 2 m-panels x all n (A-panel
// 2MB fits the 4MB XCD L2).
__global__ __launch_bounds__(256) void mam_kernel(
    const bf16* __restrict__ A,   // [M,K] bf16 (x)
    const bf16* __restrict__ B,   // [N,K] bf16 (weight row n = col n of w)
    const float* __restrict__ bias,
    float* __restrict__ out)
{
    __shared__ __align__(16) bf16 sA[4][128 * 32];  // [buffer][row*32+k]
    __shared__ __align__(16) bf16 sB[4][128 * 32];

    const int t    = threadIdx.x;
    const int lane = t & 63;
    const int w    = t >> 6;        // 0..3
    const int wm   = (w >> 1) * 64; // 0 or 64
    const int wn   = (w & 1) * 64;  // 0 or 64

    // XCD-aware swizzle: hw linear id round-robins XCDs; give each XCD a
    // contiguous chunk of 64 tiles (= 2 m-panels x 32 n-tiles).
    const int lin    = blockIdx.x + blockIdx.y * gridDim.x;   // 0..511
    const int newlin = (lin & 7) * 64 + (lin >> 3);
    const int m0 = (newlin >> 5) * 128;
    const int n0 = (newlin & 31) * 128;

    // staging: thread t -> row r = t>>2 (0..63; +64 row-block via 2nd call),
    // slot p = t&3; fetches global chunk c = p ^ ((r>>1)&3).
    const int srow   = t >> 2;
    const int spos   = t & 3;
    const int schunk = spos ^ ((srow >> 1) & 3);
    const bf16* gA = A + (size_t)(m0 + srow) * KDIM + schunk * 8;
    const bf16* gB = B + (size_t)(n0 + srow) * KDIM + schunk * 8;
    const int ldst = t * 8;  // LDS dest: lane-contiguous 16B per 2048-elem region

    // fragment addressing: row R, chunk q=lane>>4 lives at slot q ^ ((R>>1)&3);
    // (R>>1)&3 == (frow>>1)&3 (i*16, wm are multiples of 16).
    const int frow = lane & 15;
    const int q    = lane >> 4;
    const int swz  = (q ^ ((frow >> 1) & 3)) * 8;
    const int offA0 = (wm + frow) * 32 + swz;   // + i*512 per i
    const int offB0 = (wn + frow) * 32 + swz;   // + j*512 per j

    const f32x4 kZero = {0.f, 0.f, 0.f, 0.f};

    f32x4 mx[4][4], mn[4][4];
#pragma unroll
    for (int i = 0; i < 4; ++i)
#pragma unroll
        for (int j = 0; j < 4; ++j) {
            mx[i][j] = (f32x4)(-FLOATMAX);
            mn[i][j] = (f32x4)(FLOATMAX);
        }

    auto prefetch = [&](int s) {
        const int buf = s & 3;
        const bf16* ga = gA + (size_t)s * 32;
        const bf16* gb = gB + (size_t)s * 32;
        g2lds16(ga,                  &sA[buf][ldst]);          // rows 0..63
        g2lds16(ga + 64 * KDIM,      &sA[buf][2048 + ldst]);   // rows 64..127
        g2lds16(gb,                  &sB[buf][ldst]);
        g2lds16(gb + 64 * KDIM,      &sB[buf][2048 + ldst]);
    };

    auto compute = [&](int s) {
        const int buf = s & 3;
        bf16x8 bF[4];
#pragma unroll
        for (int j = 0; j < 4; ++j)
            bF[j] = *(const bf16x8*)&sB[buf][offB0 + j * 512];
#pragma unroll
        for (int i = 0; i < 4; ++i) {
            const bf16x8 a = *(const bf16x8*)&sA[buf][offA0 + i * 512];
#pragma unroll
            for (int j = 0; j < 4; ++j) {
                f32x4 sv = __builtin_amdgcn_mfma_f32_16x16x32_bf16(
                    a, bF[j], kZero, 0, 0, 0);
#pragma unroll
                for (int r = 0; r < 4; ++r) {
                    mx[i][j][r] = fmaxf(mx[i][j][r], sv[r]);
                    mn[i][j][r] = fminf(mn[i][j][r], sv[r]);
                }
            }
        }
    };

    // C/D layout: col=lane&15, row=(lane>>4)*4+reg
    const int orow = (lane >> 4) * 4;
    const int ocol = lane & 15;

    // prologue: fill 3 buffers ahead
    prefetch(0);
    prefetch(1);
    prefetch(2);
    WAITVM(8);                       // pf(0) complete; pf(1),pf(2) in flight
    __builtin_amdgcn_s_barrier();
    __builtin_amdgcn_sched_barrier(0);

#pragma unroll 1
    for (int s = 0; s < 128; ++s) {
        if (s + 3 < 128) prefetch(s + 3);
        compute(s);

        if (s == 63) {
            // store split-0 partial to out (race-free, idempotent), reset mx/mn.
            // These stores are NEWER than all pending pf -> vmcnt(8) below still
            // guarantees pf(s+1) completion.
#pragma unroll
            for (int j = 0; j < 4; ++j) {
                const int col = n0 + wn + j * 16 + ocol;
#pragma unroll
                for (int i = 0; i < 4; ++i) {
                    const int row = m0 + wm + i * 16 + orow;
#pragma unroll
                    for (int r = 0; r < 4; ++r)
                        out[(size_t)(row + r) * NDIM + col] = mx[i][j][r] + mn[i][j][r];
                    mx[i][j] = (f32x4)(-FLOATMAX);
                    mn[i][j] = (f32x4)(FLOATMAX);
                }
            }
        }

        if (s < 127) {
            // need pf(s+1) complete before next stage; newest <=8 VMEM ops are
            // pf(s+2)+pf(s+3) (4 each) -> counted wait keeps them in flight.
            if (s < 125)       { WAITVM(8); }
            else if (s == 125) { WAITVM(4); }
            else               { WAITVM(0); }   // s == 126
            __builtin_amdgcn_s_barrier();
            __builtin_amdgcn_sched_barrier(0);
        }
    }

    // epilogue: out = split0(stored) + split1(mx+mn) + bias; same-thread RMW, race-free
#pragma unroll
    for (int j = 0; j < 4; ++j) {
        const int col = n0 + wn + j * 16 + ocol;
        const float bv = bias[col];
#pragma unroll
        for (int i = 0; i < 4; ++i) {
            const int row = m0 + wm + i * 16 + orow;
#pragma unroll
            for (int r = 0; r < 4; ++r) {
                const size_t idx = (size_t)(row + r) * NDIM + col;
                out[idx] = out[idx] + (mx[i][j][r] + mn[i][j][r]) + bv;
            }
        }
    }
}

extern "C" void kernel_launch(void* const* d_in, const int* in_sizes, int n_in,
                              void* d_out, int out_size, void* d_ws, size_t ws_size,
                              hipStream_t stream) {
    const float* x    = (const float*)d_in[0];  // [M,K]
    const float* wgt  = (const float*)d_in[1];  // [N,K]
    const float* bias = (const float*)d_in[2];  // [N]
    float* out = (float*)d_out;

    bf16* xbf = (bf16*)d_ws;                        // M*K bf16 = 16 MiB
    bf16* wbf = xbf + (size_t)MDIM * KDIM;          // N*K bf16 = 32 MiB

    const int xn4 = (MDIM * KDIM) / 4;
    const int wn4 = (NDIM * KDIM) / 4;
    cvt2_f32_to_bf16<<<dim3(4096), dim3(256), 0, stream>>>(x, wgt, xbf, wbf, xn4, wn4);

    dim3 grid(NDIM / 128, MDIM / 128);  // (32, 16) -> 512 wgs, XCD-swizzled in-kernel
    mam_kernel<<<grid, dim3(256), 0, stream>>>(xbf, wbf, bias, out);
}

// Round 9
// 336.848 us; speedup vs baseline: 1.1047x; 1.1047x over previous
//
#include <hip/hip_runtime.h>
#include <cstdint>
#include <cstddef>

typedef __bf16 bf16;
typedef __bf16 bf16x4 __attribute__((ext_vector_type(4)));
typedef __bf16 bf16x8 __attribute__((ext_vector_type(8)));
typedef float  f32x4  __attribute__((ext_vector_type(4)));

#define MDIM 2048
#define NDIM 4096
#define KDIM 4096
#define FLOATMAX 3.402823466e38f

// ---------------- fp32 -> bf16 conversion (one launch for both tensors) ----------------
__global__ void cvt2_f32_to_bf16(const float* __restrict__ x, const float* __restrict__ w,
                                 bf16* __restrict__ xb, bf16* __restrict__ wb,
                                 int xn4, int wn4) {
    const int stride = gridDim.x * blockDim.x;
    int i = blockIdx.x * blockDim.x + threadIdx.x;
    for (int k = i; k < xn4; k += stride) {
        f32x4 v = reinterpret_cast<const f32x4*>(x)[k];
        reinterpret_cast<bf16x4*>(xb)[k] = __builtin_convertvector(v, bf16x4);
    }
    for (int k = i; k < wn4; k += stride) {
        f32x4 v = reinterpret_cast<const f32x4*>(w)[k];
        reinterpret_cast<bf16x4*>(wb)[k] = __builtin_convertvector(v, bf16x4);
    }
}

// async global->LDS, 16B per lane (HW: wave-uniform LDS base + lane*16)
__device__ __forceinline__ void g2lds16(const bf16* g, bf16* l) {
    __builtin_amdgcn_global_load_lds(
        (const __attribute__((address_space(1))) uint32_t*)g,
        (__attribute__((address_space(3))) uint32_t*)l, 16, 0, 0);
}

// ---------------- MAM main kernel ----------------
// Block tile 128(m) x 128(n); 256 threads = 4 waves in 2(m) x 2(n); wave tile 64x64.
// LDS pole per block-stage (BK=64): 64KB frag reads + 32KB staging writes = 96KB
// @ ~85 B/cyc/CU -> floor ~60us with 2 blocks/CU. 64x64 cuts reads 40% vs R0's 64x32.
// REGISTER LESSON (R3-R8): acc mx+mn = 128 AGPR; arch side must fit 128 with SLACK.
//   R4-R6 (8 resident B-frags): arch demand ~134 -> ~6-reg spill (200MB scratch),
//   invariant under sched_barrier placement. R7 (uncapped): 180 arch -> 1 wave/SIMD,
//   70% latency stall. R8 (BK=32+swizzle+2op bundle): regression, all reverted.
// THIS VERSION: half-major compute. Per h in {0,1} (h = one ACCBLOCK): 4 resident
// bF (16 regs) + streamed a (8) + sv (4). Arch demand ~60-70 -> ~60-reg slack,
// spill-proof. launch_bounds(256,2): 2 blocks/CU (LDS 128KB, regs ~195/wave) ->
// 2 waves/SIMD from DIFFERENT blocks -> barrier drains overlap across blocks.
// Semantics: each h is a full accblock partial (16x16x32 MFMA = 32-wide K sum),
// so mx=max(mx,sv) per h == reference max over accblocks. 2-op max/min (VALU
// ~55% of the LDS pole - acceptable cost for the register slack).
// K: 64 stages of BK=64; SPLITS=2 sequential: after stage 31 store partial
// (mx+mn) to out (race-free, idempotent), reset; epilogue adds stored+split1+bias.
// LDS double-buffered (64 KB): one barrier per stage, prefetch overlaps compute.
// Staging uses XOR chunk swizzle so fragment ds_read_b128 is 2-way conflict-free.
__global__ __launch_bounds__(256, 2) void mam_kernel(
    const bf16* __restrict__ A,   // [M,K] bf16 (x)
    const bf16* __restrict__ B,   // [N,K] bf16 (weight row n = col n of w)
    const float* __restrict__ bias,
    float* __restrict__ out)
{
    __shared__ __align__(16) bf16 sA[2][2][128 * 32];  // [parity][accblock-half]
    __shared__ __align__(16) bf16 sB[2][2][128 * 32];

    const int t    = threadIdx.x;
    const int lane = t & 63;
    const int w    = t >> 6;        // 0..3
    const int wm   = (w >> 1) * 64; // 0 or 64
    const int wn   = (w & 1) * 64;  // 0 or 64

    const int m0 = blockIdx.y * 128;
    const int n0 = blockIdx.x * 128;

    // staging: thread t -> row r = t>>2 (0..63; +64 row-block via 2nd call),
    // slot p = t&3; fetches global chunk c = p ^ ((r>>1)&3).
    // ((r+64)>>1)&3 == (r>>1)&3, so the same chunk choice serves both row-blocks.
    const int srow   = t >> 2;
    const int spos   = t & 3;
    const int schunk = spos ^ ((srow >> 1) & 3);
    const bf16* gA = A + (size_t)(m0 + srow) * KDIM + schunk * 8;
    const bf16* gB = B + (size_t)(n0 + srow) * KDIM + schunk * 8;
    const int ldst = t * 8;  // LDS dest: lane-contiguous 16B per 2048-elem region

    // fragment addressing: row R, chunk q=lane>>4 lives at slot q ^ ((R>>1)&3);
    // (R>>1)&3 == (frow>>1)&3 (i*16, wm are multiples of 16).
    const int frow = lane & 15;
    const int q    = lane >> 4;
    const int swz  = (q ^ ((frow >> 1) & 3)) * 8;
    const int offA0 = (wm + frow) * 32 + swz;   // + i*512 per i
    const int offB0 = (wn + frow) * 32 + swz;   // + j*512 per j

    const f32x4 kZero = {0.f, 0.f, 0.f, 0.f};

    f32x4 mx[4][4], mn[4][4];
#pragma unroll
    for (int i = 0; i < 4; ++i)
#pragma unroll
        for (int j = 0; j < 4; ++j) {
            mx[i][j] = (f32x4)(-FLOATMAX);
            mn[i][j] = (f32x4)(FLOATMAX);
        }

    auto prefetch = [&](int s, int pb) {
        const bf16* ga = gA + (size_t)s * 64;
        const bf16* gb = gB + (size_t)s * 64;
        // [half][row-block]: row-block 1 = rows 64..127 -> +64*KDIM src, +2048 dst
        g2lds16(ga,                  &sA[pb][0][ldst]);
        g2lds16(ga + 64 * KDIM,      &sA[pb][0][2048 + ldst]);
        g2lds16(ga + 32,             &sA[pb][1][ldst]);
        g2lds16(ga + 64 * KDIM + 32, &sA[pb][1][2048 + ldst]);
        g2lds16(gb,                  &sB[pb][0][ldst]);
        g2lds16(gb + 64 * KDIM,      &sB[pb][0][2048 + ldst]);
        g2lds16(gb + 32,             &sB[pb][1][ldst]);
        g2lds16(gb + 64 * KDIM + 32, &sB[pb][1][2048 + ldst]);
    };

    auto compute = [&](int pb) {
        // half-major: h = one ACCBLOCK. Only 4 bF resident (16 regs) + 1 a (8)
        // + 1 sv (4) -> arch-reg demand ~60-70, far under the 128 arch slots.
#pragma unroll
        for (int h = 0; h < 2; ++h) {
            bf16x8 bF[4];
#pragma unroll
            for (int j = 0; j < 4; ++j)
                bF[j] = *(const bf16x8*)&sB[pb][h][offB0 + j * 512];
#pragma unroll
            for (int i = 0; i < 4; ++i) {
                const bf16x8 a = *(const bf16x8*)&sA[pb][h][offA0 + i * 512];
#pragma unroll
                for (int j = 0; j < 4; ++j) {
                    f32x4 sv = __builtin_amdgcn_mfma_f32_16x16x32_bf16(
                        a, bF[j], kZero, 0, 0, 0);
#pragma unroll
                    for (int r = 0; r < 4; ++r) {
                        mx[i][j][r] = fmaxf(mx[i][j][r], sv[r]);
                        mn[i][j][r] = fminf(mn[i][j][r], sv[r]);
                    }
                }
            }
        }
    };

    // C/D layout: col=lane&15, row=(lane>>4)*4+reg
    const int orow = (lane >> 4) * 4;
    const int ocol = lane & 15;

    prefetch(0, 0);

    int bb = 0;
    // ---- split 0: stages 0..31 ----
#pragma unroll 1
    for (int it = 0; it < 16; ++it) {
        __syncthreads();
        prefetch(bb + 1, 1);   // bb even <= 30 -> bb+1 <= 31
        compute(0);
        ++bb;
        __syncthreads();
        prefetch(bb + 1, 0);   // bb odd <= 31 -> bb+1 <= 32 (stage 32, parity 0)
        compute(1);
        ++bb;
    }

    // store split-0 partial to out (race-free, idempotent), reset mx/mn
#pragma unroll
    for (int j = 0; j < 4; ++j) {
        const int col = n0 + wn + j * 16 + ocol;
#pragma unroll
        for (int i = 0; i < 4; ++i) {
            const int row = m0 + wm + i * 16 + orow;
#pragma unroll
            for (int r = 0; r < 4; ++r)
                out[(size_t)(row + r) * NDIM + col] = mx[i][j][r] + mn[i][j][r];
            mx[i][j] = (f32x4)(-FLOATMAX);
            mn[i][j] = (f32x4)(FLOATMAX);
        }
    }

    // ---- split 1: stages 32..63 ----
#pragma unroll 1
    for (int it = 0; it < 16; ++it) {
        __syncthreads();
        prefetch(bb + 1, 1);   // bb=32 -> prefetch 33 into parity 1
        compute(0);
        ++bb;
        __syncthreads();
        if (bb < 63) prefetch(bb + 1, 0);
        compute(1);
        ++bb;
    }

    // epilogue: out = split0(stored) + split1(mx+mn) + bias; same-thread RMW, race-free
#pragma unroll
    for (int j = 0; j < 4; ++j) {
        const int col = n0 + wn + j * 16 + ocol;
        const float bv = bias[col];
#pragma unroll
        for (int i = 0; i < 4; ++i) {
            const int row = m0 + wm + i * 16 + orow;
#pragma unroll
            for (int r = 0; r < 4; ++r) {
                const size_t idx = (size_t)(row + r) * NDIM + col;
                out[idx] = out[idx] + (mx[i][j][r] + mn[i][j][r]) + bv;
            }
        }
    }
}

extern "C" void kernel_launch(void* const* d_in, const int* in_sizes, int n_in,
                              void* d_out, int out_size, void* d_ws, size_t ws_size,
                              hipStream_t stream) {
    const float* x    = (const float*)d_in[0];  // [M,K]
    const float* wgt  = (const float*)d_in[1];  // [N,K]
    const float* bias = (const float*)d_in[2];  // [N]
    float* out = (float*)d_out;

    bf16* xbf = (bf16*)d_ws;                        // M*K bf16 = 16 MiB
    bf16* wbf = xbf + (size_t)MDIM * KDIM;          // N*K bf16 = 32 MiB

    const int xn4 = (MDIM * KDIM) / 4;
    const int wn4 = (NDIM * KDIM) / 4;
    cvt2_f32_to_bf16<<<dim3(4096), dim3(256), 0, stream>>>(x, wgt, xbf, wbf, xn4, wn4);

    dim3 grid(NDIM / 128, MDIM / 128);  // (32, 16)
    mam_kernel<<<grid, dim3(256), 0, stream>>>(xbf, wbf, bias, out);
}

// Round 11
// 281.872 us; speedup vs baseline: 1.3201x; 1.1950x over previous
//
#include <hip/hip_runtime.h>
#include <cstdint>
#include <cstddef>

typedef __bf16 bf16;
typedef __bf16 bf16x4 __attribute__((ext_vector_type(4)));
typedef __bf16 bf16x8 __attribute__((ext_vector_type(8)));
typedef float  f32x4  __attribute__((ext_vector_type(4)));

#define MDIM 2048
#define NDIM 4096
#define KDIM 4096
#define FLOATMAX 3.402823466e38f

// ---------------- fp32 -> bf16 conversion (one launch for both tensors) ----------------
__global__ void cvt2_f32_to_bf16(const float* __restrict__ x, const float* __restrict__ w,
                                 bf16* __restrict__ xb, bf16* __restrict__ wb,
                                 int xn4, int wn4) {
    const int stride = gridDim.x * blockDim.x;
    int i = blockIdx.x * blockDim.x + threadIdx.x;
    for (int k = i; k < xn4; k += stride) {
        f32x4 v = reinterpret_cast<const f32x4*>(x)[k];
        reinterpret_cast<bf16x4*>(xb)[k] = __builtin_convertvector(v, bf16x4);
    }
    for (int k = i; k < wn4; k += stride) {
        f32x4 v = reinterpret_cast<const f32x4*>(w)[k];
        reinterpret_cast<bf16x4*>(wb)[k] = __builtin_convertvector(v, bf16x4);
    }
}

// async global->LDS, 16B per lane (HW: wave-uniform LDS base + lane*16)
__device__ __forceinline__ void g2lds16(const bf16* g, bf16* l) {
    __builtin_amdgcn_global_load_lds(
        (const __attribute__((address_space(1))) uint32_t*)g,
        (__attribute__((address_space(3))) uint32_t*)l, 16, 0, 0);
}

#define WAITVM(N) asm volatile("s_waitcnt vmcnt(" #N ")" ::: "memory")

// ---------------- MAM main kernel ----------------
// GEOMETRY = R0's proven best (135.7us): block tile 128x128, 512 threads = 8 waves
// in 2(m) x 4(n), wave tile 64x32; BK=64 (2 ACCBLOCKs); acc/mx/mn register sets
// with fused max3/min3; split reset after stages 31 and 63; VGPR ~100 arch + 96
// acc, no spill (R0 WRITE_SIZE 33MB). 64x64 variants (R3-R9) all fail on the
// 128-accumulator register cliff -- closed.
// ONE CHANGE vs R0: the stall. R0 spends ~5000 cyc/stage vs ~1550 of pipe work:
// __syncthreads drains vmcnt(0) on a prefetch issued only ~1600 cyc earlier,
// while global->LDS completion under load is ~3000+ cyc; all 8 waves of the
// single resident block wait together. Fix (T3/T4): 4 LDS buffers (128 KB,
// legal on gfx950 -- the m201 8-phase template uses 128 KiB static), depth-3
// prefetch, counted vmcnt -- per stage issue pf(s+3), end with
// s_waitcnt vmcnt(8) (pf = 4 VMEM ops; 12 outstanding; pf(s+1) is complete,
// pf(s+2)/pf(s+3) stay in flight across the barrier) + raw s_barrier +
// sched_barrier(0) (compile-time fence; rule 18). Loads get ~3 stages to land.
// Buffer-reuse safety: pf(s+3) writes buf (s+3)&3 == (s-1)&3; its readers all
// passed the end-of-(s-1) barrier before any wave enters stage s.
// Hang audit: barrier sequence is uniform across all 8 waves, every WAITVM(N)
// is satisfiable, loop bounds static, no mid-loop stores.
// Staging uses XOR chunk swizzle so fragment ds_read_b128 is 2-way conflict-free.
__global__ __launch_bounds__(512, 2) void mam_kernel(
    const bf16* __restrict__ A,   // [M,K] bf16 (x)
    const bf16* __restrict__ B,   // [N,K] bf16 (weight row n = col n of w)
    const float* __restrict__ bias,
    float* __restrict__ out)
{
    __shared__ __align__(16) bf16 sA[4][2][128 * 32];  // [buffer][accblock-half]
    __shared__ __align__(16) bf16 sB[4][2][128 * 32];  // 128 KB total

    const int t    = threadIdx.x;
    const int lane = t & 63;
    const int w    = t >> 6;        // 0..7
    const int wm   = (w >> 2) * 64; // 0 or 64
    const int wn   = (w & 3) * 32;  // 0,32,64,96

    const int m0 = blockIdx.y * 128;
    const int n0 = blockIdx.x * 128;

    // staging: thread t -> row r=t>>2 (0..127), slot p=t&3; fetches chunk p^((r>>1)&3)
    const int srow   = t >> 2;
    const int spos   = t & 3;
    const int schunk = spos ^ ((srow >> 1) & 3);
    const bf16* gA = A + (size_t)(m0 + srow) * KDIM + schunk * 8;
    const bf16* gB = B + (size_t)(n0 + srow) * KDIM + schunk * 8;
    const int ldst = t * 8;  // LDS dest: lane-contiguous 16B per 4096-elem region

    // fragment addressing: row R, chunk q=lane>>4 lives at slot q ^ ((R>>1)&3);
    // (R>>1)&3 == (frow>>1)&3 (i*16, wm, wn are multiples of 16).
    const int frow = lane & 15;
    const int q    = lane >> 4;
    const int swz  = (q ^ ((frow >> 1) & 3)) * 8;
    const int offA0 = (wm + frow) * 32 + swz;   // + i*512 per i
    const int offB0 = (wn + frow) * 32 + swz;   // + j*512 per j

    const f32x4 kZero = {0.f, 0.f, 0.f, 0.f};

    f32x4 acc[4][2], mx[4][2], mn[4][2];
#pragma unroll
    for (int i = 0; i < 4; ++i)
#pragma unroll
        for (int j = 0; j < 2; ++j) {
            acc[i][j] = kZero;
            mx[i][j] = (f32x4)(-FLOATMAX);
            mn[i][j] = (f32x4)(FLOATMAX);
        }

    auto prefetch = [&](int s) {   // 4 VMEM ops
        const int buf = s & 3;
        const bf16* ga = gA + (size_t)s * 64;
        const bf16* gb = gB + (size_t)s * 64;
        g2lds16(ga,      &sA[buf][0][ldst]);
        g2lds16(ga + 32, &sA[buf][1][ldst]);
        g2lds16(gb,      &sB[buf][0][ldst]);
        g2lds16(gb + 32, &sB[buf][1][ldst]);
    };

    auto compute = [&](int buf) {
        bf16x8 aF0[4], aF1[4], bF0[2], bF1[2];
#pragma unroll
        for (int j = 0; j < 2; ++j) {
            bF0[j] = *(const bf16x8*)&sB[buf][0][offB0 + j * 512];
            bF1[j] = *(const bf16x8*)&sB[buf][1][offB0 + j * 512];
        }
#pragma unroll
        for (int i = 0; i < 4; ++i) {
            aF0[i] = *(const bf16x8*)&sA[buf][0][offA0 + i * 512];
            aF1[i] = *(const bf16x8*)&sA[buf][1][offA0 + i * 512];
        }
#pragma unroll
        for (int i = 0; i < 4; ++i) {
#pragma unroll
            for (int j = 0; j < 2; ++j) {
                f32x4 s0 = __builtin_amdgcn_mfma_f32_16x16x32_bf16(
                    aF0[i], bF0[j], kZero, 0, 0, 0);
                f32x4 s1 = __builtin_amdgcn_mfma_f32_16x16x32_bf16(
                    aF1[i], bF1[j], kZero, 0, 0, 0);
#pragma unroll
                for (int r = 0; r < 4; ++r) {
                    mx[i][j][r] = fmaxf(fmaxf(mx[i][j][r], s0[r]), s1[r]);  // v_max3_f32
                    mn[i][j][r] = fminf(fminf(mn[i][j][r], s0[r]), s1[r]);  // v_min3_f32
                }
            }
        }
    };

    auto split_reset = [&]() {   // register-only; idempotent across replays
#pragma unroll
        for (int i = 0; i < 4; ++i)
#pragma unroll
            for (int j = 0; j < 2; ++j) {
                acc[i][j] += mx[i][j] + mn[i][j];
                mx[i][j] = (f32x4)(-FLOATMAX);
                mn[i][j] = (f32x4)(FLOATMAX);
            }
    };

    // prologue: fill 3 buffers ahead; pf(0) complete, pf(1)/pf(2) in flight
    prefetch(0);
    prefetch(1);
    prefetch(2);
    WAITVM(8);
    __builtin_amdgcn_s_barrier();
    __builtin_amdgcn_sched_barrier(0);

#pragma unroll 1
    for (int s = 0; s < 64; ++s) {
        if (s < 61) prefetch(s + 3);
        compute(s & 3);
        if (s == 31 || s == 63) split_reset();
        if (s < 63) {
            // need pf(s+1) complete; keep the newer prefetches in flight.
            if (s < 61)       { WAITVM(8); }   // outstanding 12: pf(s+1..s+3)
            else if (s == 61) { WAITVM(4); }   // outstanding 8:  pf(62),pf(63)
            else              { WAITVM(0); }   // s==62, outstanding 4: pf(63)
            __builtin_amdgcn_s_barrier();
            __builtin_amdgcn_sched_barrier(0);
        }
    }

    // epilogue: C/D layout col=lane&15, row=(lane>>4)*4+reg
    const int orow = (lane >> 4) * 4;
    const int ocol = lane & 15;
#pragma unroll
    for (int j = 0; j < 2; ++j) {
        const int col = n0 + wn + j * 16 + ocol;
        const float bv = bias[col];
#pragma unroll
        for (int i = 0; i < 4; ++i) {
            const int row = m0 + wm + i * 16 + orow;
#pragma unroll
            for (int r = 0; r < 4; ++r) {
                out[(size_t)(row + r) * NDIM + col] = acc[i][j][r] + bv;
            }
        }
    }
}

extern "C" void kernel_launch(void* const* d_in, const int* in_sizes, int n_in,
                              void* d_out, int out_size, void* d_ws, size_t ws_size,
                              hipStream_t stream) {
    const float* x    = (const float*)d_in[0];  // [M,K]
    const float* wgt  = (const float*)d_in[1];  // [N,K]
    const float* bias = (const float*)d_in[2];  // [N]
    float* out = (float*)d_out;

    bf16* xbf = (bf16*)d_ws;                        // M*K bf16 = 16 MiB
    bf16* wbf = xbf + (size_t)MDIM * KDIM;          // N*K bf16 = 32 MiB

    const int xn4 = (MDIM * KDIM) / 4;
    const int wn4 = (NDIM * KDIM) / 4;
    cvt2_f32_to_bf16<<<dim3(4096), dim3(256), 0, stream>>>(x, wgt, xbf, wbf, xn4, wn4);

    dim3 grid(NDIM / 128, MDIM / 128);  // (32, 16)
    mam_kernel<<<grid, dim3(512), 0, stream>>>(xbf, wbf, bias, out);
}